// Round 10
// baseline (297.456 us; speedup 1.0000x reference)
//
#include <hip/hip_runtime.h>
#include <hip/hip_fp16.h>

// Problem constants
#define NF 32
#define DM 256
#define HH 128
#define BB 16
#define TT 512
#define BT 8192            // B*T tokens
#define OUT_W_OFF 2097152  // B*T*D
#define EPS 1e-5f

typedef __bf16 bf16x8 __attribute__((ext_vector_type(8)));
typedef float  f32x16 __attribute__((ext_vector_type(16)));
typedef __fp16 f16x2 __attribute__((ext_vector_type(2)));
typedef __fp16 f16x8 __attribute__((ext_vector_type(8)));

__device__ __forceinline__ float eluf(float z){ return z > 0.f ? z : __expf(z) - 1.f; }
__device__ __forceinline__ float sigm(float z){ return 1.f/(1.f + __expf(-z)); }
__device__ __forceinline__ unsigned f2bf(float x){
  unsigned u = __float_as_uint(x);
  u += 0x7fffu + ((u>>16)&1u);   // RNE
  return u>>16;
}

// Reduce-sum across each 32-lane half, result broadcast to all lanes.
// xor1/xor2 via DPP quad_perm (1 v_add each), xor4/8/16 via ds_swizzle
// (1 DS + 1 v_add) — cheaper than __shfl_xor's lshl+ds_bpermute lowering.
__device__ __forceinline__ float rsum32(float v){
  int a;
  a = __builtin_amdgcn_update_dpp(0, __float_as_int(v), 0xB1, 0xF, 0xF, true); // quad_perm [1,0,3,2] = xor1
  v += __int_as_float(a);
  a = __builtin_amdgcn_update_dpp(0, __float_as_int(v), 0x4E, 0xF, 0xF, true); // quad_perm [2,3,0,1] = xor2
  v += __int_as_float(a);
  v += __int_as_float(__builtin_amdgcn_ds_swizzle(__float_as_int(v), 0x101F)); // xor4
  v += __int_as_float(__builtin_amdgcn_ds_swizzle(__float_as_int(v), 0x201F)); // xor8
  v += __int_as_float(__builtin_amdgcn_ds_swizzle(__float_as_int(v), 0x401F)); // xor16
  return v;
}

// Build A = elu(x*w1+b1) (MT*32 tokens x 128 k) in MFMA A-frag order, shared via LDS:
// Apack[mt][ks][lane][j] ; m=mt*32+(lane&31), k=ks*16+(lane>>5)*8+j
template<int MT, int NTHR>
__device__ __forceinline__ void build_A(uint4* Apack, const float* __restrict__ x,
                                        const float* __restrict__ w1, const float* __restrict__ b1,
                                        int f, int tok0, int tid){
  #pragma unroll
  for (int p = 0; p < (MT*512)/NTHR; ++p){
    int slot = tid + p*NTHR;
    int l  = slot & 63;
    int ks = (slot>>6)&7;
    int mt = slot>>9;
    int m  = mt*32 + (l&31);
    int k0 = ks*16 + (l>>5)*8;
    float xv = x[(tok0+m)*NF + f];
    const float* wp = w1 + f*HH + k0;
    const float* bp = b1 + f*HH + k0;
    float4 wa = *(const float4*)wp, wb = *(const float4*)(wp+4);
    float4 ba = *(const float4*)bp, bb = *(const float4*)(bp+4);
    bf16x8 v;
    v[0] = (__bf16)eluf(fmaf(xv, wa.x, ba.x));
    v[1] = (__bf16)eluf(fmaf(xv, wa.y, ba.y));
    v[2] = (__bf16)eluf(fmaf(xv, wa.z, ba.z));
    v[3] = (__bf16)eluf(fmaf(xv, wa.w, ba.w));
    v[4] = (__bf16)eluf(fmaf(xv, wb.x, bb.x));
    v[5] = (__bf16)eluf(fmaf(xv, wb.y, bb.y));
    v[6] = (__bf16)eluf(fmaf(xv, wb.z, bb.z));
    v[7] = (__bf16)eluf(fmaf(xv, wb.w, bb.w));
    Apack[slot] = __builtin_bit_cast(uint4, v);
  }
}

// ---------------- prep: repack w2/wg (f32) -> bf16 B-fragment layout ----------------
// Also zeroes pooled/hw_pre/sk_pre/counter (replaces hipMemsetAsync dispatches).
__global__ __launch_bounds__(256) void k_prep(const float* __restrict__ w2,
                                              const float* __restrict__ wgm,
                                              uint4* __restrict__ Wpk,
                                              float* __restrict__ pooled,
                                              float* __restrict__ hw_pre,
                                              float* __restrict__ sk_pre,
                                              unsigned* __restrict__ counter){
  __shared__ float ssrc[2][128][32];
  const int tid = threadIdx.x;
  const int f = blockIdx.x, c = blockIdx.y;
  // --- zero the accumulator buffers ---
  {
    const int gb = blockIdx.y*gridDim.x + blockIdx.x;   // 0..255
    const int gt = gb*256 + tid;                        // 0..65535
    pooled[gt] = 0.f;
    pooled[gt + 65536] = 0.f;
    if (gt < 4096) hw_pre[gt] = 0.f;
    else if (gt < 4608) sk_pre[gt - 4096] = 0.f;
    if (gt == 0) *counter = 0u;
  }
  #pragma unroll
  for (int it = 0; it < 32; ++it){
    int idx = tid + it*256;
    int arr = idx >> 12;
    int rem = idx & 4095;
    int k = rem >> 5, dd = rem & 31;
    const float* src = arr ? wgm : w2;
    ssrc[arr][k][dd] = src[(f*HH + k)*DM + c*32 + dd];
  }
  __syncthreads();
  #pragma unroll
  for (int p = 0; p < 4; ++p){
    int oc = tid + p*256;
    int nt = oc>>9, ks = (oc>>6)&7, l = oc&63;
    int k0 = ks*16 + (l>>5)*8, dd = l&31;
    float v[8];
    #pragma unroll
    for (int j=0;j<8;++j) v[j] = ssrc[nt][k0+j][dd];
    uint4 pk;
    pk.x = f2bf(v[0]) | (f2bf(v[1])<<16);
    pk.y = f2bf(v[2]) | (f2bf(v[3])<<16);
    pk.z = f2bf(v[4]) | (f2bf(v[5])<<16);
    pk.w = f2bf(v[6]) | (f2bf(v[7])<<16);
    Wpk[(f*8 + c)*1024 + oc] = pk;
  }
}

// ---------------- pass1: GRN + LN + store shat(fp16) + pooled sums ----------------
// 512 threads / 8 waves; 128 tokens. wave = (tt = wid>>1, ch = wid&1):
// 32 tokens x 4 c-chunks. Arch VGPR + 32 AGPR must stay <= 128-class ->
// 4 waves/SIMD, 2 blocks/CU = 16 waves/CU (R4..R9-verified: occ ~40%).
// R10 VALU diet: b2/bg folded into MFMA acc init (-128 adds); dump row-reduce
// via DPP+ds_swizzle (rsum32, -~120 VALU); trailing sched_barrier removed so
// next ci's Wpk loads can hoist above the epilogue (first barrier kept as the
// register-pressure guard).
__global__ __launch_bounds__(512, 2) void k_pass1(const float* __restrict__ x,  const float* __restrict__ w1,
    const float* __restrict__ b1, const float* __restrict__ b2, const float* __restrict__ bg,
    const float* __restrict__ wsk, const float* __restrict__ bsk,
    const float* __restrict__ lng, const float* __restrict__ lnb,
    const uint4* __restrict__ Wpk,
    float* __restrict__ pooled, uint4* __restrict__ stk4){
  __shared__ uint4 smem[4096];          // 64 KB: Apack (first 2048 = 32 KB), then fp16 stage [128 t][256 d]
  __shared__ float xs[128];
  __shared__ float poolbuf[256];
  const int tid = threadIdx.x, lane = tid&63, wid = tid>>6;
  const int tt = wid>>1, ch = wid&1;    // token tile / d-half
  const int col = lane&31, q = lane>>5;
  const int f = blockIdx.y;
  const int tok0 = blockIdx.x*128;
  const int b = tok0 >> 9;
  if (tid < 256) poolbuf[tid] = 0.f;
  if (tid < 128) xs[tid] = x[(tok0 + tid)*NF + f];

  build_A<4,512>(smem, x, w1, b1, f, tok0, tid);
  __syncthreads();
  bf16x8 afr[8];
  #pragma unroll
  for (int ks=0; ks<8; ++ks) afr[ks] = __builtin_bit_cast(bf16x8, smem[(tt*8+ks)*64 + lane]);
  __syncthreads();   // all Apack reads done; stage writes may begin

  __fp16* stage = (__fp16*)smem;        // [128 t][256 d]
  #pragma unroll 1
  for (int ci=0; ci<4; ++ci){
    const int c = ch*4 + ci;
    const int d = c*32 + col;
    const float b2v = b2[f*DM+d], bgv = bg[f*DM+d];
    const uint4* wb = Wpk + (f*8 + c)*1024;
    bf16x8 bfr[8];
    #pragma unroll
    for (int ks=0;ks<8;++ks) bfr[ks] = __builtin_bit_cast(bf16x8, wb[ks*64 + lane]);
    f32x16 acc0;
    #pragma unroll
    for (int r=0;r<16;++r) acc0[r] = b2v;      // bias folded into MFMA C
    #pragma unroll
    for (int ks=0;ks<8;++ks) acc0 = __builtin_amdgcn_mfma_f32_32x32x16_bf16(afr[ks], bfr[ks], acc0, 0,0,0);
    __builtin_amdgcn_sched_barrier(0);  // keep second B-batch from hoisting (reg pressure)
    #pragma unroll
    for (int ks=0;ks<8;++ks) bfr[ks] = __builtin_bit_cast(bf16x8, wb[512 + ks*64 + lane]);
    f32x16 acc1;
    #pragma unroll
    for (int r=0;r<16;++r) acc1[r] = bgv;      // bias folded into MFMA C
    #pragma unroll
    for (int ks=0;ks<8;++ks) acc1 = __builtin_amdgcn_mfma_f32_32x32x16_bf16(afr[ks], bfr[ks], acc1, 0,0,0);
    #pragma unroll
    for (int i=0;i<8;++i){
      const int r0 = 2*i, r1 = r0+1;
      const int t0 = tt*32 + (r0&3) + 8*(i>>1) + 4*q;
      stage[ t0   *256 + d] = (__fp16)(sigm(acc1[r0])*acc0[r0]);
      stage[(t0+1)*256 + d] = (__fp16)(sigm(acc1[r1])*acc0[r1]);
    }
  }
  __syncthreads();   // stage + xs complete

  // --- dump: add skip, LN stats via rsum32, apply LN, write + pool ---
  const int oc = tid & 31;          // d-octet, constant per thread
  float4 ga = *(const float4*)(lng + f*DM + oc*8);
  float4 gb = *(const float4*)(lng + f*DM + oc*8 + 4);
  float4 la = *(const float4*)(lnb + f*DM + oc*8);
  float4 lb = *(const float4*)(lnb + f*DM + oc*8 + 4);
  float4 wa = *(const float4*)(wsk + f*DM + oc*8);
  float4 wbv = *(const float4*)(wsk + f*DM + oc*8 + 4);
  float4 sa = *(const float4*)(bsk + f*DM + oc*8);
  float4 sb = *(const float4*)(bsk + f*DM + oc*8 + 4);
  float gj[8] = {ga.x,ga.y,ga.z,ga.w,gb.x,gb.y,gb.z,gb.w};
  float bj[8] = {la.x,la.y,la.z,la.w,lb.x,lb.y,lb.z,lb.w};
  float wj[8] = {wa.x,wa.y,wa.z,wa.w,wbv.x,wbv.y,wbv.z,wbv.w};
  float cj[8] = {sa.x,sa.y,sa.z,sa.w,sb.x,sb.y,sb.z,sb.w};
  float ps[8];
  #pragma unroll
  for (int j=0;j<8;++j) ps[j]=0.f;
  #pragma unroll
  for (int p=0;p<8;++p){
    int slot = tid + p*512;          // [t(128)][oc(32)]
    int t = slot >> 5;
    uint4 v = smem[slot];
    f16x8 s8 = __builtin_bit_cast(f16x8, v);
    float xt = xs[t];
    float s[8];
    float ssum = 0.f, ssq = 0.f;
    #pragma unroll
    for (int j=0;j<8;++j){
      s[j] = fmaf(xt, wj[j], cj[j]) + (float)s8[j];
      ssum += s[j];
      ssq = fmaf(s[j], s[j], ssq);
    }
    // token row t is fully owned by this 32-lane group
    ssum = rsum32(ssum);
    ssq  = rsum32(ssq);
    float mu = ssum * (1.f/256.f);
    float var = fmaf(-mu, mu, ssq*(1.f/256.f));
    float rs = rsqrtf(fmaxf(var, 0.f) + EPS);
    float nmr = -mu*rs;
    float sh[8];
    #pragma unroll
    for (int j=0;j<8;++j){
      sh[j] = fmaf(fmaf(s[j], rs, nmr), gj[j], bj[j]);
      ps[j] += sh[j];
    }
    uint4 pk;
    pk.x = __builtin_bit_cast(unsigned, __builtin_amdgcn_cvt_pkrtz(sh[0], sh[1]));
    pk.y = __builtin_bit_cast(unsigned, __builtin_amdgcn_cvt_pkrtz(sh[2], sh[3]));
    pk.z = __builtin_bit_cast(unsigned, __builtin_amdgcn_cvt_pkrtz(sh[4], sh[5]));
    pk.w = __builtin_bit_cast(unsigned, __builtin_amdgcn_cvt_pkrtz(sh[6], sh[7]));
    // chunked layout: [(tok0+t)>>2][f][t&3][d] -> 4096 uint4 per 4-token chunk
    const int tg = tok0 + t;
    stk4[(size_t)(tg>>2)*4096 + (size_t)f*128 + (size_t)(tg&3)*32 + oc] = pk;
  }
  // fold lane pairs (l, l+32) sharing oc, then one LDS atomic per cell
  #pragma unroll
  for (int j=0;j<8;++j) ps[j] += __shfl_xor(ps[j], 32);
  if (q == 0){
    #pragma unroll
    for (int j=0;j<8;++j) atomicAdd(&poolbuf[oc*8 + j], ps[j]);
  }
  __syncthreads();
  if (tid < 256) atomicAdd(&pooled[b*8192 + f*DM + tid], poolbuf[tid]);
}

// ---------------- pass2: flat_pooled @ W1 / @ Ws (k-major, W1 read once) + fused tail ----------------
// Grid = 128 k-chunk blocks (64 rows each). Each block stages fl[16][64] in LDS;
// thread owns output column n=tid with acc[16] — W1 streamed exactly once,
// fully coalesced, 16 FMAs per load. Last block to finish runs the weight GRN +
// LN + softmax tail (counter==127); hw_pre/sk_pre read back via atomicAdd(p,0.f)
// to bypass non-coherent L1.
__global__ __launch_bounds__(256) void k_pass2(const float* __restrict__ pooled,
    const float* __restrict__ W1, const float* __restrict__ Wsm,
    float* __restrict__ hw_pre, float* __restrict__ sk_pre,
    const float* __restrict__ B1, const float* __restrict__ W2, const float* __restrict__ B2,
    const float* __restrict__ Wg, const float* __restrict__ Bg, const float* __restrict__ Bs,
    const float* __restrict__ LNg, const float* __restrict__ LNb,
    unsigned* __restrict__ counter, float* __restrict__ out, float* __restrict__ wsel){
  __shared__ float fl[16][64];
  __shared__ float hwt[16][256];
  __shared__ int amLast;
  const int tid = threadIdx.x;
  const int k0 = blockIdx.x * 64;
  #pragma unroll
  for (int p=0;p<4;++p){
    int idx = tid + p*256;           // [b(16)][i(64)]
    int bb = idx >> 6, ii = idx & 63;
    fl[bb][ii] = pooled[bb*8192 + k0 + ii] * (1.f/512.f);
  }
  __syncthreads();
  // W1 part: thread owns column n = tid; W1 rows streamed coalesced (1 KB/row)
  float acc[16];
  #pragma unroll
  for (int b=0;b<16;++b) acc[b]=0.f;
  const float* wp = W1 + (size_t)k0*DM + tid;
  #pragma unroll 4
  for (int i=0;i<64;++i){
    float w = wp[(size_t)i*DM];
    #pragma unroll
    for (int b=0;b<16;++b) acc[b] = fmaf(fl[b][i], w, acc[b]);
  }
  #pragma unroll
  for (int b=0;b<16;++b) atomicAdd(&hw_pre[b*DM + tid], acc[b]);
  // Ws part: thread = (colj = tid&31, bh = tid>>5); two passes cover 16 b
  const int colj = tid & 31, bh = tid >> 5;
  const float* wsp = Wsm + (size_t)k0*NF + colj;
  #pragma unroll 1
  for (int pass=0; pass<2; ++pass){
    const int bb = bh + pass*8;
    float a2 = 0.f;
    #pragma unroll 4
    for (int i=0;i<64;++i) a2 = fmaf(fl[bb][i], wsp[(size_t)i*NF], a2);
    atomicAdd(&sk_pre[bb*NF + colj], a2);
  }

  // ---- last-block-done tail ----
  __threadfence();                      // drain this block's atomics (release)
  __syncthreads();
  if (tid == 0){
    unsigned old = atomicAdd(counter, 1u);
    amLast = (old == 127u) ? 1 : 0;
  }
  __syncthreads();
  if (!amLast) return;
  // gather hw: atomic loads bypass L1 (producers' atomics landed in L2)
  #pragma unroll
  for (int p=0;p<16;++p){
    float v = atomicAdd(&hw_pre[p*DM + tid], 0.f);
    hwt[p][tid] = eluf(v + B1[tid]);
  }
  __syncthreads();
  const int j = tid & 31;
  const int bl = tid >> 5;              // 0..7
  #pragma unroll 1
  for (int pass=0; pass<2; ++pass){
    const int bb = bl + pass*8;
    float ap = B2[j], ag = Bg[j];
    #pragma unroll 4
    for (int i=0;i<256;++i){ float h = hwt[bb][i]; ap = fmaf(h, W2[i*NF+j], ap); ag = fmaf(h, Wg[i*NF+j], ag); }
    float gw = sigm(ag);
    float v = atomicAdd(&sk_pre[bb*NF + j], 0.f) + Bs[j] + gw*ap;
    float s1 = v;
    s1 += __shfl_xor(s1,1); s1 += __shfl_xor(s1,2); s1 += __shfl_xor(s1,4); s1 += __shfl_xor(s1,8); s1 += __shfl_xor(s1,16);
    float mean = s1*(1.f/32.f);
    float dv = v - mean;
    float s2 = dv*dv;
    s2 += __shfl_xor(s2,1); s2 += __shfl_xor(s2,2); s2 += __shfl_xor(s2,4); s2 += __shfl_xor(s2,8); s2 += __shfl_xor(s2,16);
    float wn = fmaf(dv * rsqrtf(s2*(1.f/32.f) + EPS), LNg[j], LNb[j]);
    float mx = wn;
    mx = fmaxf(mx, __shfl_xor(mx,1)); mx = fmaxf(mx, __shfl_xor(mx,2)); mx = fmaxf(mx, __shfl_xor(mx,4));
    mx = fmaxf(mx, __shfl_xor(mx,8)); mx = fmaxf(mx, __shfl_xor(mx,16));
    float e = __expf(wn - mx);
    float se = e;
    se += __shfl_xor(se,1); se += __shfl_xor(se,2); se += __shfl_xor(se,4); se += __shfl_xor(se,8); se += __shfl_xor(se,16);
    float wgt = e / se;
    out[OUT_W_OFF + bb*NF + j] = wgt;
    wsel[bb*NF + j] = wgt;
  }
}

// ---------------- combine: out[t,d] = sum_f w[b,f] * shat[t>>2][f][t&3][d] ----------------
// Chunked stk4: block = one 4-token chunk = 64 KB contiguous.
__global__ __launch_bounds__(256) void k_comb(const uint4* __restrict__ stk4,
    const float* __restrict__ wsel, float* __restrict__ out){
  __shared__ float wloc[NF];
  const int tid = threadIdx.x, lane = tid&63;
  const int tc = blockIdx.x;            // token chunk (4 tokens)
  const int ts = tid>>6;                // t&3
  const int t = tc*4 + ts;
  const int b = t >> 9;
  if (tid < NF) wloc[tid] = wsel[b*NF + tid];
  __syncthreads();
  const int oc = lane&31, fh = lane>>5;
  float acc[8];
  #pragma unroll
  for (int j=0;j<8;++j) acc[j]=0.f;
  #pragma unroll
  for (int j=0;j<16;++j){
    int f = fh*16 + j;
    uint4 v = stk4[(size_t)tc*4096 + f*128 + ts*32 + oc];
    f16x8 hv = __builtin_bit_cast(f16x8, v);
    float wf = wloc[f];
    #pragma unroll
    for (int jj=0;jj<8;++jj) acc[jj] = fmaf(wf, (float)hv[jj], acc[jj]);
  }
  #pragma unroll
  for (int jj=0;jj<8;++jj) acc[jj] += __shfl_xor(acc[jj], 32);
  if (fh == 0){
    float4* o = (float4*)(out + (size_t)t*DM + oc*8);
    o[0] = make_float4(acc[0],acc[1],acc[2],acc[3]);
    o[1] = make_float4(acc[4],acc[5],acc[6],acc[7]);
  }
}

extern "C" void kernel_launch(void* const* d_in, const int* in_sizes, int n_in,
                              void* d_out, int out_size, void* d_ws, size_t ws_size,
                              hipStream_t stream) {
  const float* x   = (const float*)d_in[0];
  const float* w1  = (const float*)d_in[1];
  const float* b1  = (const float*)d_in[2];
  const float* w2  = (const float*)d_in[3];
  const float* b2  = (const float*)d_in[4];
  const float* wgm = (const float*)d_in[5];
  const float* bg  = (const float*)d_in[6];
  const float* wsk = (const float*)d_in[7];
  const float* bsk = (const float*)d_in[8];
  const float* lng = (const float*)d_in[9];
  const float* lnb = (const float*)d_in[10];
  const float* W1  = (const float*)d_in[11];
  const float* B1  = (const float*)d_in[12];
  const float* W2  = (const float*)d_in[13];
  const float* B2  = (const float*)d_in[14];
  const float* Wg  = (const float*)d_in[15];
  const float* Bg  = (const float*)d_in[16];
  const float* Wsm = (const float*)d_in[17];
  const float* Bs  = (const float*)d_in[18];
  const float* LNg = (const float*)d_in[19];
  const float* LNb = (const float*)d_in[20];
  float* out = (float*)d_out;

  char* ws = (char*)d_ws;
  uint4* Wpk      = (uint4*)ws;                     // 4 MB bf16-packed weights
  uint4* stk4     = (uint4*)(ws + 4194304);         // 128 MiB fp16 shat [t>>2][f][t&3][d]
  float* pooled   = (float*)(ws + 138412032);       // 512 KB
  float* hw_pre   = (float*)(ws + 138936320);       // 16 KB
  float* sk_pre   = (float*)(ws + 138952704);       // 2 KB
  float* wsel     = (float*)(ws + 138954752);       // 2 KB
  unsigned* cnt   = (unsigned*)(ws + 138956800);    // 4 B

  k_prep<<<dim3(32,8), 256, 0, stream>>>(w2, wgm, Wpk, pooled, hw_pre, sk_pre, cnt);
  k_pass1<<<dim3(64,32), 512, 0, stream>>>(x, w1, b1, b2, bg, wsk, bsk, lng, lnb,
                                           Wpk, pooled, stk4);
  k_pass2<<<dim3(128), 256, 0, stream>>>(pooled, W1, Wsm, hw_pre, sk_pre,
                                         B1, W2, B2, Wg, Bg, Bs, LNg, LNb,
                                         cnt, out, wsel);
  k_comb<<<2048, 256, 0, stream>>>(stk4, wsel, out);
}

// Round 11
// 293.473 us; speedup vs baseline: 1.0136x; 1.0136x over previous
//
#include <hip/hip_runtime.h>
#include <hip/hip_fp16.h>

// Problem constants
#define NF 32
#define DM 256
#define HH 128
#define BB 16
#define TT 512
#define BT 8192            // B*T tokens
#define OUT_W_OFF 2097152  // B*T*D
#define EPS 1e-5f

typedef __bf16 bf16x8 __attribute__((ext_vector_type(8)));
typedef float  f32x16 __attribute__((ext_vector_type(16)));
typedef __fp16 f16x2 __attribute__((ext_vector_type(2)));
typedef __fp16 f16x8 __attribute__((ext_vector_type(8)));

__device__ __forceinline__ float eluf(float z){ return z > 0.f ? z : __expf(z) - 1.f; }
__device__ __forceinline__ float sigm(float z){ return 1.f/(1.f + __expf(-z)); }
__device__ __forceinline__ unsigned f2bf(float x){
  unsigned u = __float_as_uint(x);
  u += 0x7fffu + ((u>>16)&1u);   // RNE
  return u>>16;
}

// Reduce-sum across each 32-lane half, result broadcast to all lanes.
// xor1/xor2 via DPP quad_perm (1 v_add each), xor4/8/16 via ds_swizzle
// (1 DS + 1 v_add) — cheaper than __shfl_xor's lshl+ds_bpermute lowering.
__device__ __forceinline__ float rsum32(float v){
  int a;
  a = __builtin_amdgcn_update_dpp(0, __float_as_int(v), 0xB1, 0xF, 0xF, true); // quad_perm [1,0,3,2] = xor1
  v += __int_as_float(a);
  a = __builtin_amdgcn_update_dpp(0, __float_as_int(v), 0x4E, 0xF, 0xF, true); // quad_perm [2,3,0,1] = xor2
  v += __int_as_float(a);
  v += __int_as_float(__builtin_amdgcn_ds_swizzle(__float_as_int(v), 0x101F)); // xor4
  v += __int_as_float(__builtin_amdgcn_ds_swizzle(__float_as_int(v), 0x201F)); // xor8
  v += __int_as_float(__builtin_amdgcn_ds_swizzle(__float_as_int(v), 0x401F)); // xor16
  return v;
}

// Build A = elu(x*w1+b1) (MT*32 tokens x 128 k) in MFMA A-frag order, shared via LDS:
// Apack[mt][ks][lane][j] ; m=mt*32+(lane&31), k=ks*16+(lane>>5)*8+j
template<int MT, int NTHR>
__device__ __forceinline__ void build_A(uint4* Apack, const float* __restrict__ x,
                                        const float* __restrict__ w1, const float* __restrict__ b1,
                                        int f, int tok0, int tid){
  #pragma unroll
  for (int p = 0; p < (MT*512)/NTHR; ++p){
    int slot = tid + p*NTHR;
    int l  = slot & 63;
    int ks = (slot>>6)&7;
    int mt = slot>>9;
    int m  = mt*32 + (l&31);
    int k0 = ks*16 + (l>>5)*8;
    float xv = x[(tok0+m)*NF + f];
    const float* wp = w1 + f*HH + k0;
    const float* bp = b1 + f*HH + k0;
    float4 wa = *(const float4*)wp, wb = *(const float4*)(wp+4);
    float4 ba = *(const float4*)bp, bb = *(const float4*)(bp+4);
    bf16x8 v;
    v[0] = (__bf16)eluf(fmaf(xv, wa.x, ba.x));
    v[1] = (__bf16)eluf(fmaf(xv, wa.y, ba.y));
    v[2] = (__bf16)eluf(fmaf(xv, wa.z, ba.z));
    v[3] = (__bf16)eluf(fmaf(xv, wa.w, ba.w));
    v[4] = (__bf16)eluf(fmaf(xv, wb.x, bb.x));
    v[5] = (__bf16)eluf(fmaf(xv, wb.y, bb.y));
    v[6] = (__bf16)eluf(fmaf(xv, wb.z, bb.z));
    v[7] = (__bf16)eluf(fmaf(xv, wb.w, bb.w));
    Apack[slot] = __builtin_bit_cast(uint4, v);
  }
}

// ---------------- prep: repack w2/wg (f32) -> bf16 B-fragment layout ----------------
// Also zeroes pooled/hw_pre/sk_pre/counter (replaces hipMemsetAsync dispatches).
__global__ __launch_bounds__(256) void k_prep(const float* __restrict__ w2,
                                              const float* __restrict__ wgm,
                                              uint4* __restrict__ Wpk,
                                              float* __restrict__ pooled,
                                              float* __restrict__ hw_pre,
                                              float* __restrict__ sk_pre,
                                              unsigned* __restrict__ counter){
  __shared__ float ssrc[2][128][32];
  const int tid = threadIdx.x;
  const int f = blockIdx.x, c = blockIdx.y;
  // --- zero the accumulator buffers ---
  {
    const int gb = blockIdx.y*gridDim.x + blockIdx.x;   // 0..255
    const int gt = gb*256 + tid;                        // 0..65535
    pooled[gt] = 0.f;
    pooled[gt + 65536] = 0.f;
    if (gt < 4096) hw_pre[gt] = 0.f;
    else if (gt < 4608) sk_pre[gt - 4096] = 0.f;
    if (gt == 0) *counter = 0u;
  }
  #pragma unroll
  for (int it = 0; it < 32; ++it){
    int idx = tid + it*256;
    int arr = idx >> 12;
    int rem = idx & 4095;
    int k = rem >> 5, dd = rem & 31;
    const float* src = arr ? wgm : w2;
    ssrc[arr][k][dd] = src[(f*HH + k)*DM + c*32 + dd];
  }
  __syncthreads();
  #pragma unroll
  for (int p = 0; p < 4; ++p){
    int oc = tid + p*256;
    int nt = oc>>9, ks = (oc>>6)&7, l = oc&63;
    int k0 = ks*16 + (l>>5)*8, dd = l&31;
    float v[8];
    #pragma unroll
    for (int j=0;j<8;++j) v[j] = ssrc[nt][k0+j][dd];
    uint4 pk;
    pk.x = f2bf(v[0]) | (f2bf(v[1])<<16);
    pk.y = f2bf(v[2]) | (f2bf(v[3])<<16);
    pk.z = f2bf(v[4]) | (f2bf(v[5])<<16);
    pk.w = f2bf(v[6]) | (f2bf(v[7])<<16);
    Wpk[(f*8 + c)*1024 + oc] = pk;
  }
}

// ---------------- pass1: GRN + LN + store shat(fp16) + pooled sums ----------------
// 512 threads / 8 waves; 128 tokens. wave = (tt = wid>>1, ch = wid&1):
// 32 tokens x 4 c-chunks. Arch VGPR + AGPR must stay in the 128 unified class ->
// 4 waves/SIMD, 2 blocks/CU = 16 waves/CU (R4..R9-verified: occ ~40%).
// R11 = R10 minus the trailing-fence removal: BOTH sched_barriers restored
// (R10 showed dropping the trailing one lets next-ci loads hoist across the
// epilogue -> live-range growth -> 192-class -> occ 22%, dur +13us).
// Kept from R10: b2/bg folded into MFMA acc init; rsum32 DPP/ds_swizzle reduce.
__global__ __launch_bounds__(512, 2) void k_pass1(const float* __restrict__ x,  const float* __restrict__ w1,
    const float* __restrict__ b1, const float* __restrict__ b2, const float* __restrict__ bg,
    const float* __restrict__ wsk, const float* __restrict__ bsk,
    const float* __restrict__ lng, const float* __restrict__ lnb,
    const uint4* __restrict__ Wpk,
    float* __restrict__ pooled, uint4* __restrict__ stk4){
  __shared__ uint4 smem[4096];          // 64 KB: Apack (first 2048 = 32 KB), then fp16 stage [128 t][256 d]
  __shared__ float xs[128];
  __shared__ float poolbuf[256];
  const int tid = threadIdx.x, lane = tid&63, wid = tid>>6;
  const int tt = wid>>1, ch = wid&1;    // token tile / d-half
  const int col = lane&31, q = lane>>5;
  const int f = blockIdx.y;
  const int tok0 = blockIdx.x*128;
  const int b = tok0 >> 9;
  if (tid < 256) poolbuf[tid] = 0.f;
  if (tid < 128) xs[tid] = x[(tok0 + tid)*NF + f];

  build_A<4,512>(smem, x, w1, b1, f, tok0, tid);
  __syncthreads();
  bf16x8 afr[8];
  #pragma unroll
  for (int ks=0; ks<8; ++ks) afr[ks] = __builtin_bit_cast(bf16x8, smem[(tt*8+ks)*64 + lane]);
  __syncthreads();   // all Apack reads done; stage writes may begin

  __fp16* stage = (__fp16*)smem;        // [128 t][256 d]
  #pragma unroll 1
  for (int ci=0; ci<4; ++ci){
    const int c = ch*4 + ci;
    const int d = c*32 + col;
    const float b2v = b2[f*DM+d], bgv = bg[f*DM+d];
    const uint4* wb = Wpk + (f*8 + c)*1024;
    bf16x8 bfr[8];
    #pragma unroll
    for (int ks=0;ks<8;++ks) bfr[ks] = __builtin_bit_cast(bf16x8, wb[ks*64 + lane]);
    f32x16 acc0;
    #pragma unroll
    for (int r=0;r<16;++r) acc0[r] = b2v;      // bias folded into MFMA C
    #pragma unroll
    for (int ks=0;ks<8;++ks) acc0 = __builtin_amdgcn_mfma_f32_32x32x16_bf16(afr[ks], bfr[ks], acc0, 0,0,0);
    __builtin_amdgcn_sched_barrier(0);  // keep second B-batch from hoisting (reg pressure)
    #pragma unroll
    for (int ks=0;ks<8;++ks) bfr[ks] = __builtin_bit_cast(bf16x8, wb[512 + ks*64 + lane]);
    f32x16 acc1;
    #pragma unroll
    for (int r=0;r<16;++r) acc1[r] = bgv;      // bias folded into MFMA C
    #pragma unroll
    for (int ks=0;ks<8;++ks) acc1 = __builtin_amdgcn_mfma_f32_32x32x16_bf16(afr[ks], bfr[ks], acc1, 0,0,0);
    __builtin_amdgcn_sched_barrier(0);  // pin epilogue: no next-ci load hoist (R10 lesson)
    #pragma unroll
    for (int i=0;i<8;++i){
      const int r0 = 2*i, r1 = r0+1;
      const int t0 = tt*32 + (r0&3) + 8*(i>>1) + 4*q;
      stage[ t0   *256 + d] = (__fp16)(sigm(acc1[r0])*acc0[r0]);
      stage[(t0+1)*256 + d] = (__fp16)(sigm(acc1[r1])*acc0[r1]);
    }
  }
  __syncthreads();   // stage + xs complete

  // --- dump: add skip, LN stats via rsum32, apply LN, write + pool ---
  const int oc = tid & 31;          // d-octet, constant per thread
  float4 ga = *(const float4*)(lng + f*DM + oc*8);
  float4 gb = *(const float4*)(lng + f*DM + oc*8 + 4);
  float4 la = *(const float4*)(lnb + f*DM + oc*8);
  float4 lb = *(const float4*)(lnb + f*DM + oc*8 + 4);
  float4 wa = *(const float4*)(wsk + f*DM + oc*8);
  float4 wbv = *(const float4*)(wsk + f*DM + oc*8 + 4);
  float4 sa = *(const float4*)(bsk + f*DM + oc*8);
  float4 sb = *(const float4*)(bsk + f*DM + oc*8 + 4);
  float gj[8] = {ga.x,ga.y,ga.z,ga.w,gb.x,gb.y,gb.z,gb.w};
  float bj[8] = {la.x,la.y,la.z,la.w,lb.x,lb.y,lb.z,lb.w};
  float wj[8] = {wa.x,wa.y,wa.z,wa.w,wbv.x,wbv.y,wbv.z,wbv.w};
  float cj[8] = {sa.x,sa.y,sa.z,sa.w,sb.x,sb.y,sb.z,sb.w};
  float ps[8];
  #pragma unroll
  for (int j=0;j<8;++j) ps[j]=0.f;
  #pragma unroll
  for (int p=0;p<8;++p){
    int slot = tid + p*512;          // [t(128)][oc(32)]
    int t = slot >> 5;
    uint4 v = smem[slot];
    f16x8 s8 = __builtin_bit_cast(f16x8, v);
    float xt = xs[t];
    float s[8];
    float ssum = 0.f, ssq = 0.f;
    #pragma unroll
    for (int j=0;j<8;++j){
      s[j] = fmaf(xt, wj[j], cj[j]) + (float)s8[j];
      ssum += s[j];
      ssq = fmaf(s[j], s[j], ssq);
    }
    // token row t is fully owned by this 32-lane group
    ssum = rsum32(ssum);
    ssq  = rsum32(ssq);
    float mu = ssum * (1.f/256.f);
    float var = fmaf(-mu, mu, ssq*(1.f/256.f));
    float rs = rsqrtf(fmaxf(var, 0.f) + EPS);
    float nmr = -mu*rs;
    float sh[8];
    #pragma unroll
    for (int j=0;j<8;++j){
      sh[j] = fmaf(fmaf(s[j], rs, nmr), gj[j], bj[j]);
      ps[j] += sh[j];
    }
    uint4 pk;
    pk.x = __builtin_bit_cast(unsigned, __builtin_amdgcn_cvt_pkrtz(sh[0], sh[1]));
    pk.y = __builtin_bit_cast(unsigned, __builtin_amdgcn_cvt_pkrtz(sh[2], sh[3]));
    pk.z = __builtin_bit_cast(unsigned, __builtin_amdgcn_cvt_pkrtz(sh[4], sh[5]));
    pk.w = __builtin_bit_cast(unsigned, __builtin_amdgcn_cvt_pkrtz(sh[6], sh[7]));
    // chunked layout: [(tok0+t)>>2][f][t&3][d] -> 4096 uint4 per 4-token chunk
    const int tg = tok0 + t;
    stk4[(size_t)(tg>>2)*4096 + (size_t)f*128 + (size_t)(tg&3)*32 + oc] = pk;
  }
  // fold lane pairs (l, l+32) sharing oc, then one LDS atomic per cell
  #pragma unroll
  for (int j=0;j<8;++j) ps[j] += __shfl_xor(ps[j], 32);
  if (q == 0){
    #pragma unroll
    for (int j=0;j<8;++j) atomicAdd(&poolbuf[oc*8 + j], ps[j]);
  }
  __syncthreads();
  if (tid < 256) atomicAdd(&pooled[b*8192 + f*DM + tid], poolbuf[tid]);
}

// ---------------- pass2: flat_pooled @ W1 / @ Ws (k-major, W1 read once) + fused tail ----------------
// Grid = 128 k-chunk blocks (64 rows each). Each block stages fl[16][64] in LDS;
// thread owns output column n=tid with acc[16] — W1 streamed exactly once,
// fully coalesced, 16 FMAs per load. Last block to finish runs the weight GRN +
// LN + softmax tail (counter==127); hw_pre/sk_pre read back via atomicAdd(p,0.f)
// to bypass non-coherent L1.
__global__ __launch_bounds__(256) void k_pass2(const float* __restrict__ pooled,
    const float* __restrict__ W1, const float* __restrict__ Wsm,
    float* __restrict__ hw_pre, float* __restrict__ sk_pre,
    const float* __restrict__ B1, const float* __restrict__ W2, const float* __restrict__ B2,
    const float* __restrict__ Wg, const float* __restrict__ Bg, const float* __restrict__ Bs,
    const float* __restrict__ LNg, const float* __restrict__ LNb,
    unsigned* __restrict__ counter, float* __restrict__ out, float* __restrict__ wsel){
  __shared__ float fl[16][64];
  __shared__ float hwt[16][256];
  __shared__ int amLast;
  const int tid = threadIdx.x;
  const int k0 = blockIdx.x * 64;
  #pragma unroll
  for (int p=0;p<4;++p){
    int idx = tid + p*256;           // [b(16)][i(64)]
    int bb = idx >> 6, ii = idx & 63;
    fl[bb][ii] = pooled[bb*8192 + k0 + ii] * (1.f/512.f);
  }
  __syncthreads();
  // W1 part: thread owns column n = tid; W1 rows streamed coalesced (1 KB/row)
  float acc[16];
  #pragma unroll
  for (int b=0;b<16;++b) acc[b]=0.f;
  const float* wp = W1 + (size_t)k0*DM + tid;
  #pragma unroll 4
  for (int i=0;i<64;++i){
    float w = wp[(size_t)i*DM];
    #pragma unroll
    for (int b=0;b<16;++b) acc[b] = fmaf(fl[b][i], w, acc[b]);
  }
  #pragma unroll
  for (int b=0;b<16;++b) atomicAdd(&hw_pre[b*DM + tid], acc[b]);
  // Ws part: thread = (colj = tid&31, bh = tid>>5); two passes cover 16 b
  const int colj = tid & 31, bh = tid >> 5;
  const float* wsp = Wsm + (size_t)k0*NF + colj;
  #pragma unroll 1
  for (int pass=0; pass<2; ++pass){
    const int bb = bh + pass*8;
    float a2 = 0.f;
    #pragma unroll 4
    for (int i=0;i<64;++i) a2 = fmaf(fl[bb][i], wsp[(size_t)i*NF], a2);
    atomicAdd(&sk_pre[bb*NF + colj], a2);
  }

  // ---- last-block-done tail ----
  __threadfence();                      // drain this block's atomics (release)
  __syncthreads();
  if (tid == 0){
    unsigned old = atomicAdd(counter, 1u);
    amLast = (old == 127u) ? 1 : 0;
  }
  __syncthreads();
  if (!amLast) return;
  // gather hw: atomic loads bypass L1 (producers' atomics landed in L2)
  #pragma unroll
  for (int p=0;p<16;++p){
    float v = atomicAdd(&hw_pre[p*DM + tid], 0.f);
    hwt[p][tid] = eluf(v + B1[tid]);
  }
  __syncthreads();
  const int j = tid & 31;
  const int bl = tid >> 5;              // 0..7
  #pragma unroll 1
  for (int pass=0; pass<2; ++pass){
    const int bb = bl + pass*8;
    float ap = B2[j], ag = Bg[j];
    #pragma unroll 4
    for (int i=0;i<256;++i){ float h = hwt[bb][i]; ap = fmaf(h, W2[i*NF+j], ap); ag = fmaf(h, Wg[i*NF+j], ag); }
    float gw = sigm(ag);
    float v = atomicAdd(&sk_pre[bb*NF + j], 0.f) + Bs[j] + gw*ap;
    float s1 = v;
    s1 += __shfl_xor(s1,1); s1 += __shfl_xor(s1,2); s1 += __shfl_xor(s1,4); s1 += __shfl_xor(s1,8); s1 += __shfl_xor(s1,16);
    float mean = s1*(1.f/32.f);
    float dv = v - mean;
    float s2 = dv*dv;
    s2 += __shfl_xor(s2,1); s2 += __shfl_xor(s2,2); s2 += __shfl_xor(s2,4); s2 += __shfl_xor(s2,8); s2 += __shfl_xor(s2,16);
    float wn = fmaf(dv * rsqrtf(s2*(1.f/32.f) + EPS), LNg[j], LNb[j]);
    float mx = wn;
    mx = fmaxf(mx, __shfl_xor(mx,1)); mx = fmaxf(mx, __shfl_xor(mx,2)); mx = fmaxf(mx, __shfl_xor(mx,4));
    mx = fmaxf(mx, __shfl_xor(mx,8)); mx = fmaxf(mx, __shfl_xor(mx,16));
    float e = __expf(wn - mx);
    float se = e;
    se += __shfl_xor(se,1); se += __shfl_xor(se,2); se += __shfl_xor(se,4); se += __shfl_xor(se,8); se += __shfl_xor(se,16);
    float wgt = e / se;
    out[OUT_W_OFF + bb*NF + j] = wgt;
    wsel[bb*NF + j] = wgt;
  }
}

// ---------------- combine: out[t,d] = sum_f w[b,f] * shat[t>>2][f][t&3][d] ----------------
// Chunked stk4: block = one 4-token chunk = 64 KB contiguous.
__global__ __launch_bounds__(256) void k_comb(const uint4* __restrict__ stk4,
    const float* __restrict__ wsel, float* __restrict__ out){
  __shared__ float wloc[NF];
  const int tid = threadIdx.x, lane = tid&63;
  const int tc = blockIdx.x;            // token chunk (4 tokens)
  const int ts = tid>>6;                // t&3
  const int t = tc*4 + ts;
  const int b = t >> 9;
  if (tid < NF) wloc[tid] = wsel[b*NF + tid];
  __syncthreads();
  const int oc = lane&31, fh = lane>>5;
  float acc[8];
  #pragma unroll
  for (int j=0;j<8;++j) acc[j]=0.f;
  #pragma unroll
  for (int j=0;j<16;++j){
    int f = fh*16 + j;
    uint4 v = stk4[(size_t)tc*4096 + f*128 + ts*32 + oc];
    f16x8 hv = __builtin_bit_cast(f16x8, v);
    float wf = wloc[f];
    #pragma unroll
    for (int jj=0;jj<8;++jj) acc[jj] = fmaf(wf, (float)hv[jj], acc[jj]);
  }
  #pragma unroll
  for (int jj=0;jj<8;++jj) acc[jj] += __shfl_xor(acc[jj], 32);
  if (fh == 0){
    float4* o = (float4*)(out + (size_t)t*DM + oc*8);
    o[0] = make_float4(acc[0],acc[1],acc[2],acc[3]);
    o[1] = make_float4(acc[4],acc[5],acc[6],acc[7]);
  }
}

extern "C" void kernel_launch(void* const* d_in, const int* in_sizes, int n_in,
                              void* d_out, int out_size, void* d_ws, size_t ws_size,
                              hipStream_t stream) {
  const float* x   = (const float*)d_in[0];
  const float* w1  = (const float*)d_in[1];
  const float* b1  = (const float*)d_in[2];
  const float* w2  = (const float*)d_in[3];
  const float* b2  = (const float*)d_in[4];
  const float* wgm = (const float*)d_in[5];
  const float* bg  = (const float*)d_in[6];
  const float* wsk = (const float*)d_in[7];
  const float* bsk = (const float*)d_in[8];
  const float* lng = (const float*)d_in[9];
  const float* lnb = (const float*)d_in[10];
  const float* W1  = (const float*)d_in[11];
  const float* B1  = (const float*)d_in[12];
  const float* W2  = (const float*)d_in[13];
  const float* B2  = (const float*)d_in[14];
  const float* Wg  = (const float*)d_in[15];
  const float* Bg  = (const float*)d_in[16];
  const float* Wsm = (const float*)d_in[17];
  const float* Bs  = (const float*)d_in[18];
  const float* LNg = (const float*)d_in[19];
  const float* LNb = (const float*)d_in[20];
  float* out = (float*)d_out;

  char* ws = (char*)d_ws;
  uint4* Wpk      = (uint4*)ws;                     // 4 MB bf16-packed weights
  uint4* stk4     = (uint4*)(ws + 4194304);         // 128 MiB fp16 shat [t>>2][f][t&3][d]
  float* pooled   = (float*)(ws + 138412032);       // 512 KB
  float* hw_pre   = (float*)(ws + 138936320);       // 16 KB
  float* sk_pre   = (float*)(ws + 138952704);       // 2 KB
  float* wsel     = (float*)(ws + 138954752);       // 2 KB
  unsigned* cnt   = (unsigned*)(ws + 138956800);    // 4 B

  k_prep<<<dim3(32,8), 256, 0, stream>>>(w2, wgm, Wpk, pooled, hw_pre, sk_pre, cnt);
  k_pass1<<<dim3(64,32), 512, 0, stream>>>(x, w1, b1, b2, bg, wsk, bsk, lng, lnb,
                                           Wpk, pooled, stk4);
  k_pass2<<<dim3(128), 256, 0, stream>>>(pooled, W1, Wsm, hw_pre, sk_pre,
                                         B1, W2, B2, Wg, Bg, Bs, LNg, LNb,
                                         cnt, out, wsel);
  k_comb<<<2048, 256, 0, stream>>>(stk4, wsel, out);
}

// Round 13
// 261.507 us; speedup vs baseline: 1.1375x; 1.1222x over previous
//
#include <hip/hip_runtime.h>
#include <hip/hip_fp16.h>

// Problem constants
#define NF 32
#define DM 256
#define HH 128
#define BB 16
#define TT 512
#define BT 8192            // B*T tokens
#define OUT_W_OFF 2097152  // B*T*D
#define EPS 1e-5f

typedef __bf16 bf16x8 __attribute__((ext_vector_type(8)));
typedef float  f32x16 __attribute__((ext_vector_type(16)));
typedef __fp16 f16x2 __attribute__((ext_vector_type(2)));
typedef __fp16 f16x8 __attribute__((ext_vector_type(8)));

__device__ __forceinline__ float eluf(float z){ return z > 0.f ? z : __expf(z) - 1.f; }
__device__ __forceinline__ float sigm(float z){ return 1.f/(1.f + __expf(-z)); }
__device__ __forceinline__ unsigned f2bf(float x){
  unsigned u = __float_as_uint(x);
  u += 0x7fffu + ((u>>16)&1u);   // RNE
  return u>>16;
}

// Reduce-sum across each 32-lane half, result broadcast to all lanes.
// xor1/xor2 via DPP quad_perm (1 v_add each), xor4/8/16 via ds_swizzle
// (1 DS + 1 v_add) — cheaper than __shfl_xor's lshl+ds_bpermute lowering.
__device__ __forceinline__ float rsum32(float v){
  int a;
  a = __builtin_amdgcn_update_dpp(0, __float_as_int(v), 0xB1, 0xF, 0xF, true); // quad_perm [1,0,3,2] = xor1
  v += __int_as_float(a);
  a = __builtin_amdgcn_update_dpp(0, __float_as_int(v), 0x4E, 0xF, 0xF, true); // quad_perm [2,3,0,1] = xor2
  v += __int_as_float(a);
  v += __int_as_float(__builtin_amdgcn_ds_swizzle(__float_as_int(v), 0x101F)); // xor4
  v += __int_as_float(__builtin_amdgcn_ds_swizzle(__float_as_int(v), 0x201F)); // xor8
  v += __int_as_float(__builtin_amdgcn_ds_swizzle(__float_as_int(v), 0x401F)); // xor16
  return v;
}

// Build A = elu(x*w1+b1) (MT*32 tokens x 128 k) in MFMA A-frag order, shared via LDS:
// Apack[mt][ks][lane][j] ; m=mt*32+(lane&31), k=ks*16+(lane>>5)*8+j
template<int MT, int NTHR>
__device__ __forceinline__ void build_A(uint4* Apack, const float* __restrict__ x,
                                        const float* __restrict__ w1, const float* __restrict__ b1,
                                        int f, int tok0, int tid){
  #pragma unroll
  for (int p = 0; p < (MT*512)/NTHR; ++p){
    int slot = tid + p*NTHR;
    int l  = slot & 63;
    int ks = (slot>>6)&7;
    int mt = slot>>9;
    int m  = mt*32 + (l&31);
    int k0 = ks*16 + (l>>5)*8;
    float xv = x[(tok0+m)*NF + f];
    const float* wp = w1 + f*HH + k0;
    const float* bp = b1 + f*HH + k0;
    float4 wa = *(const float4*)wp, wb = *(const float4*)(wp+4);
    float4 ba = *(const float4*)bp, bb = *(const float4*)(bp+4);
    bf16x8 v;
    v[0] = (__bf16)eluf(fmaf(xv, wa.x, ba.x));
    v[1] = (__bf16)eluf(fmaf(xv, wa.y, ba.y));
    v[2] = (__bf16)eluf(fmaf(xv, wa.z, ba.z));
    v[3] = (__bf16)eluf(fmaf(xv, wa.w, ba.w));
    v[4] = (__bf16)eluf(fmaf(xv, wb.x, bb.x));
    v[5] = (__bf16)eluf(fmaf(xv, wb.y, bb.y));
    v[6] = (__bf16)eluf(fmaf(xv, wb.z, bb.z));
    v[7] = (__bf16)eluf(fmaf(xv, wb.w, bb.w));
    Apack[slot] = __builtin_bit_cast(uint4, v);
  }
}

// ---------------- prep: repack w2/wg (f32) -> bf16 B-fragment layout ----------------
// Also zeroes pooled/hw_pre/sk_pre (replaces hipMemsetAsync dispatches).
__global__ __launch_bounds__(256) void k_prep(const float* __restrict__ w2,
                                              const float* __restrict__ wgm,
                                              uint4* __restrict__ Wpk,
                                              float* __restrict__ pooled,
                                              float* __restrict__ hw_pre,
                                              float* __restrict__ sk_pre){
  __shared__ float ssrc[2][128][32];
  const int tid = threadIdx.x;
  const int f = blockIdx.x, c = blockIdx.y;
  // --- zero the accumulator buffers ---
  {
    const int gb = blockIdx.y*gridDim.x + blockIdx.x;   // 0..255
    const int gt = gb*256 + tid;                        // 0..65535
    pooled[gt] = 0.f;
    pooled[gt + 65536] = 0.f;
    if (gt < 4096) hw_pre[gt] = 0.f;
    else if (gt < 4608) sk_pre[gt - 4096] = 0.f;
  }
  #pragma unroll
  for (int it = 0; it < 32; ++it){
    int idx = tid + it*256;
    int arr = idx >> 12;
    int rem = idx & 4095;
    int k = rem >> 5, dd = rem & 31;
    const float* src = arr ? wgm : w2;
    ssrc[arr][k][dd] = src[(f*HH + k)*DM + c*32 + dd];
  }
  __syncthreads();
  #pragma unroll
  for (int p = 0; p < 4; ++p){
    int oc = tid + p*256;
    int nt = oc>>9, ks = (oc>>6)&7, l = oc&63;
    int k0 = ks*16 + (l>>5)*8, dd = l&31;
    float v[8];
    #pragma unroll
    for (int j=0;j<8;++j) v[j] = ssrc[nt][k0+j][dd];
    uint4 pk;
    pk.x = f2bf(v[0]) | (f2bf(v[1])<<16);
    pk.y = f2bf(v[2]) | (f2bf(v[3])<<16);
    pk.z = f2bf(v[4]) | (f2bf(v[5])<<16);
    pk.w = f2bf(v[6]) | (f2bf(v[7])<<16);
    Wpk[(f*8 + c)*1024 + oc] = pk;
  }
}

// ---------------- pass1: GRN + LN + store shat(fp16) + pooled sums ----------------
// R13 == R11 verbatim (proven: 118 us, occ ~40%, VGPR 60, passed 4x).
// 512 threads / 8 waves; 128 tokens. wave = (tt = wid>>1, ch = wid&1):
// 32 tokens x 4 c-chunks. Arch VGPR + AGPR stay in the 128 unified class ->
// 4 waves/SIMD, 2 blocks/CU = 16 waves/CU.
// Both sched_barriers required (R10: dropping the trailing one -> live-range
// growth -> 192-class -> occ 22%, +13us). Bias-fold + rsum32 (R11: -6us).
// R12's grid-orientation swap exposed a scheduling-sensitive failure -> reverted.
__global__ __launch_bounds__(512, 2) void k_pass1(const float* __restrict__ x,  const float* __restrict__ w1,
    const float* __restrict__ b1, const float* __restrict__ b2, const float* __restrict__ bg,
    const float* __restrict__ wsk, const float* __restrict__ bsk,
    const float* __restrict__ lng, const float* __restrict__ lnb,
    const uint4* __restrict__ Wpk,
    float* __restrict__ pooled, uint4* __restrict__ stk4){
  __shared__ uint4 smem[4096];          // 64 KB: Apack (first 2048 = 32 KB), then fp16 stage [128 t][256 d]
  __shared__ float xs[128];
  __shared__ float poolbuf[256];
  const int tid = threadIdx.x, lane = tid&63, wid = tid>>6;
  const int tt = wid>>1, ch = wid&1;    // token tile / d-half
  const int col = lane&31, q = lane>>5;
  const int f = blockIdx.y;
  const int tok0 = blockIdx.x*128;
  const int b = tok0 >> 9;
  if (tid < 256) poolbuf[tid] = 0.f;
  if (tid < 128) xs[tid] = x[(tok0 + tid)*NF + f];

  build_A<4,512>(smem, x, w1, b1, f, tok0, tid);
  __syncthreads();
  bf16x8 afr[8];
  #pragma unroll
  for (int ks=0; ks<8; ++ks) afr[ks] = __builtin_bit_cast(bf16x8, smem[(tt*8+ks)*64 + lane]);
  __syncthreads();   // all Apack reads done; stage writes may begin

  __fp16* stage = (__fp16*)smem;        // [128 t][256 d]
  #pragma unroll 1
  for (int ci=0; ci<4; ++ci){
    const int c = ch*4 + ci;
    const int d = c*32 + col;
    const float b2v = b2[f*DM+d], bgv = bg[f*DM+d];
    const uint4* wb = Wpk + (f*8 + c)*1024;
    bf16x8 bfr[8];
    #pragma unroll
    for (int ks=0;ks<8;++ks) bfr[ks] = __builtin_bit_cast(bf16x8, wb[ks*64 + lane]);
    f32x16 acc0;
    #pragma unroll
    for (int r=0;r<16;++r) acc0[r] = b2v;      // bias folded into MFMA C
    #pragma unroll
    for (int ks=0;ks<8;++ks) acc0 = __builtin_amdgcn_mfma_f32_32x32x16_bf16(afr[ks], bfr[ks], acc0, 0,0,0);
    __builtin_amdgcn_sched_barrier(0);  // keep second B-batch from hoisting (reg pressure)
    #pragma unroll
    for (int ks=0;ks<8;++ks) bfr[ks] = __builtin_bit_cast(bf16x8, wb[512 + ks*64 + lane]);
    f32x16 acc1;
    #pragma unroll
    for (int r=0;r<16;++r) acc1[r] = bgv;      // bias folded into MFMA C
    #pragma unroll
    for (int ks=0;ks<8;++ks) acc1 = __builtin_amdgcn_mfma_f32_32x32x16_bf16(afr[ks], bfr[ks], acc1, 0,0,0);
    __builtin_amdgcn_sched_barrier(0);  // pin epilogue: no next-ci load hoist (R10 lesson)
    #pragma unroll
    for (int i=0;i<8;++i){
      const int r0 = 2*i, r1 = r0+1;
      const int t0 = tt*32 + (r0&3) + 8*(i>>1) + 4*q;
      stage[ t0   *256 + d] = (__fp16)(sigm(acc1[r0])*acc0[r0]);
      stage[(t0+1)*256 + d] = (__fp16)(sigm(acc1[r1])*acc0[r1]);
    }
  }
  __syncthreads();   // stage + xs complete

  // --- dump: add skip, LN stats via rsum32, apply LN, write + pool ---
  const int oc = tid & 31;          // d-octet, constant per thread
  float4 ga = *(const float4*)(lng + f*DM + oc*8);
  float4 gb = *(const float4*)(lng + f*DM + oc*8 + 4);
  float4 la = *(const float4*)(lnb + f*DM + oc*8);
  float4 lb = *(const float4*)(lnb + f*DM + oc*8 + 4);
  float4 wa = *(const float4*)(wsk + f*DM + oc*8);
  float4 wbv = *(const float4*)(wsk + f*DM + oc*8 + 4);
  float4 sa = *(const float4*)(bsk + f*DM + oc*8);
  float4 sb = *(const float4*)(bsk + f*DM + oc*8 + 4);
  float gj[8] = {ga.x,ga.y,ga.z,ga.w,gb.x,gb.y,gb.z,gb.w};
  float bj[8] = {la.x,la.y,la.z,la.w,lb.x,lb.y,lb.z,lb.w};
  float wj[8] = {wa.x,wa.y,wa.z,wa.w,wbv.x,wbv.y,wbv.z,wbv.w};
  float cj[8] = {sa.x,sa.y,sa.z,sa.w,sb.x,sb.y,sb.z,sb.w};
  float ps[8];
  #pragma unroll
  for (int j=0;j<8;++j) ps[j]=0.f;
  #pragma unroll
  for (int p=0;p<8;++p){
    int slot = tid + p*512;          // [t(128)][oc(32)]
    int t = slot >> 5;
    uint4 v = smem[slot];
    f16x8 s8 = __builtin_bit_cast(f16x8, v);
    float xt = xs[t];
    float s[8];
    float ssum = 0.f, ssq = 0.f;
    #pragma unroll
    for (int j=0;j<8;++j){
      s[j] = fmaf(xt, wj[j], cj[j]) + (float)s8[j];
      ssum += s[j];
      ssq = fmaf(s[j], s[j], ssq);
    }
    // token row t is fully owned by this 32-lane group
    ssum = rsum32(ssum);
    ssq  = rsum32(ssq);
    float mu = ssum * (1.f/256.f);
    float var = fmaf(-mu, mu, ssq*(1.f/256.f));
    float rs = rsqrtf(fmaxf(var, 0.f) + EPS);
    float nmr = -mu*rs;
    float sh[8];
    #pragma unroll
    for (int j=0;j<8;++j){
      sh[j] = fmaf(fmaf(s[j], rs, nmr), gj[j], bj[j]);
      ps[j] += sh[j];
    }
    uint4 pk;
    pk.x = __builtin_bit_cast(unsigned, __builtin_amdgcn_cvt_pkrtz(sh[0], sh[1]));
    pk.y = __builtin_bit_cast(unsigned, __builtin_amdgcn_cvt_pkrtz(sh[2], sh[3]));
    pk.z = __builtin_bit_cast(unsigned, __builtin_amdgcn_cvt_pkrtz(sh[4], sh[5]));
    pk.w = __builtin_bit_cast(unsigned, __builtin_amdgcn_cvt_pkrtz(sh[6], sh[7]));
    // chunked layout: [(tok0+t)>>2][f][t&3][d] -> 4096 uint4 per 4-token chunk
    const int tg = tok0 + t;
    stk4[(size_t)(tg>>2)*4096 + (size_t)f*128 + (size_t)(tg&3)*32 + oc] = pk;
  }
  // fold lane pairs (l, l+32) sharing oc, then one LDS atomic per cell
  #pragma unroll
  for (int j=0;j<8;++j) ps[j] += __shfl_xor(ps[j], 32);
  if (q == 0){
    #pragma unroll
    for (int j=0;j<8;++j) atomicAdd(&poolbuf[oc*8 + j], ps[j]);
  }
  __syncthreads();
  if (tid < 256) atomicAdd(&pooled[b*8192 + f*DM + tid], poolbuf[tid]);
}

// ---------------- pass2a: flat_pooled @ W1 / @ Ws (k-major, W1 read once) ----------------
// R13: fused last-block tail REMOVED (R12 exposed its scheduling sensitivity);
// determinism via kernel boundary instead. Main loop = R9's proven k-major form:
// grid = 128 k-chunk blocks (64 rows each); block stages fl[16][64] in LDS;
// thread owns output column n=tid with acc[16] — W1 streamed exactly once,
// fully coalesced, 16 FMAs per load.
__global__ __launch_bounds__(256) void k_pass2a(const float* __restrict__ pooled,
    const float* __restrict__ W1, const float* __restrict__ Wsm,
    float* __restrict__ hw_pre, float* __restrict__ sk_pre){
  __shared__ float fl[16][64];
  const int tid = threadIdx.x;
  const int k0 = blockIdx.x * 64;
  #pragma unroll
  for (int p=0;p<4;++p){
    int idx = tid + p*256;           // [b(16)][i(64)]
    int bb = idx >> 6, ii = idx & 63;
    fl[bb][ii] = pooled[bb*8192 + k0 + ii] * (1.f/512.f);
  }
  __syncthreads();
  // W1 part: thread owns column n = tid; W1 rows streamed coalesced (1 KB/row)
  float acc[16];
  #pragma unroll
  for (int b=0;b<16;++b) acc[b]=0.f;
  const float* wp = W1 + (size_t)k0*DM + tid;
  #pragma unroll 4
  for (int i=0;i<64;++i){
    float w = wp[(size_t)i*DM];
    #pragma unroll
    for (int b=0;b<16;++b) acc[b] = fmaf(fl[b][i], w, acc[b]);
  }
  #pragma unroll
  for (int b=0;b<16;++b) atomicAdd(&hw_pre[b*DM + tid], acc[b]);
  // Ws part: thread = (colj = tid&31, bh = tid>>5); two passes cover 16 b
  const int colj = tid & 31, bh = tid >> 5;
  const float* wsp = Wsm + (size_t)k0*NF + colj;
  #pragma unroll 1
  for (int pass=0; pass<2; ++pass){
    const int bb = bh + pass*8;
    float a2 = 0.f;
    #pragma unroll 4
    for (int i=0;i<64;++i) a2 = fmaf(fl[bb][i], wsp[(size_t)i*NF], a2);
    atomicAdd(&sk_pre[bb*NF + colj], a2);
  }
}

// ---------------- pass2b: weight GRN + LN + softmax -> weights ----------------
__global__ __launch_bounds__(64) void k_pass2b(const float* __restrict__ hw_pre, const float* __restrict__ sk_pre,
    const float* __restrict__ B1, const float* __restrict__ W2, const float* __restrict__ B2,
    const float* __restrict__ Wg, const float* __restrict__ Bg, const float* __restrict__ Bs,
    const float* __restrict__ LNg, const float* __restrict__ LNb,
    float* __restrict__ out, float* __restrict__ wsel){
  __shared__ float hw[256];
  const int tid = threadIdx.x, b = blockIdx.x;
  for (int i=tid;i<256;i+=64) hw[i] = eluf(hw_pre[b*DM+i] + B1[i]);
  __syncthreads();
  if (tid < 32){
    const int j = tid;
    float ap = B2[j], ag = Bg[j];
    #pragma unroll 4
    for (int i=0;i<256;++i){ float h = hw[i]; ap = fmaf(h, W2[i*NF+j], ap); ag = fmaf(h, Wg[i*NF+j], ag); }
    float gw = sigm(ag);
    float v = sk_pre[b*NF+j] + Bs[j] + gw*ap;
    float s1 = v;
    s1 += __shfl_xor(s1,1); s1 += __shfl_xor(s1,2); s1 += __shfl_xor(s1,4); s1 += __shfl_xor(s1,8); s1 += __shfl_xor(s1,16);
    float mean = s1*(1.f/32.f);
    float dv = v - mean;
    float s2 = dv*dv;
    s2 += __shfl_xor(s2,1); s2 += __shfl_xor(s2,2); s2 += __shfl_xor(s2,4); s2 += __shfl_xor(s2,8); s2 += __shfl_xor(s2,16);
    float wn = fmaf(dv * rsqrtf(s2*(1.f/32.f) + EPS), LNg[j], LNb[j]);
    float mx = wn;
    mx = fmaxf(mx, __shfl_xor(mx,1)); mx = fmaxf(mx, __shfl_xor(mx,2)); mx = fmaxf(mx, __shfl_xor(mx,4));
    mx = fmaxf(mx, __shfl_xor(mx,8)); mx = fmaxf(mx, __shfl_xor(mx,16));
    float e = __expf(wn - mx);
    float se = e;
    se += __shfl_xor(se,1); se += __shfl_xor(se,2); se += __shfl_xor(se,4); se += __shfl_xor(se,8); se += __shfl_xor(se,16);
    float wgt = e / se;
    out[OUT_W_OFF + b*NF + j] = wgt;
    wsel[b*NF + j] = wgt;
  }
}

// ---------------- combine: out[t,d] = sum_f w[b,f] * shat[t>>2][f][t&3][d] ----------------
// Chunked stk4: block = one 4-token chunk = 64 KB contiguous.
__global__ __launch_bounds__(256) void k_comb(const uint4* __restrict__ stk4,
    const float* __restrict__ wsel, float* __restrict__ out){
  __shared__ float wloc[NF];
  const int tid = threadIdx.x, lane = tid&63;
  const int tc = blockIdx.x;            // token chunk (4 tokens)
  const int ts = tid>>6;                // t&3
  const int t = tc*4 + ts;
  const int b = t >> 9;
  if (tid < NF) wloc[tid] = wsel[b*NF + tid];
  __syncthreads();
  const int oc = lane&31, fh = lane>>5;
  float acc[8];
  #pragma unroll
  for (int j=0;j<8;++j) acc[j]=0.f;
  #pragma unroll
  for (int j=0;j<16;++j){
    int f = fh*16 + j;
    uint4 v = stk4[(size_t)tc*4096 + f*128 + ts*32 + oc];
    f16x8 hv = __builtin_bit_cast(f16x8, v);
    float wf = wloc[f];
    #pragma unroll
    for (int jj=0;jj<8;++jj) acc[jj] = fmaf(wf, (float)hv[jj], acc[jj]);
  }
  #pragma unroll
  for (int jj=0;jj<8;++jj) acc[jj] += __shfl_xor(acc[jj], 32);
  if (fh == 0){
    float4* o = (float4*)(out + (size_t)t*DM + oc*8);
    o[0] = make_float4(acc[0],acc[1],acc[2],acc[3]);
    o[1] = make_float4(acc[4],acc[5],acc[6],acc[7]);
  }
}

extern "C" void kernel_launch(void* const* d_in, const int* in_sizes, int n_in,
                              void* d_out, int out_size, void* d_ws, size_t ws_size,
                              hipStream_t stream) {
  const float* x   = (const float*)d_in[0];
  const float* w1  = (const float*)d_in[1];
  const float* b1  = (const float*)d_in[2];
  const float* w2  = (const float*)d_in[3];
  const float* b2  = (const float*)d_in[4];
  const float* wgm = (const float*)d_in[5];
  const float* bg  = (const float*)d_in[6];
  const float* wsk = (const float*)d_in[7];
  const float* bsk = (const float*)d_in[8];
  const float* lng = (const float*)d_in[9];
  const float* lnb = (const float*)d_in[10];
  const float* W1  = (const float*)d_in[11];
  const float* B1  = (const float*)d_in[12];
  const float* W2  = (const float*)d_in[13];
  const float* B2  = (const float*)d_in[14];
  const float* Wg  = (const float*)d_in[15];
  const float* Bg  = (const float*)d_in[16];
  const float* Wsm = (const float*)d_in[17];
  const float* Bs  = (const float*)d_in[18];
  const float* LNg = (const float*)d_in[19];
  const float* LNb = (const float*)d_in[20];
  float* out = (float*)d_out;

  char* ws = (char*)d_ws;
  uint4* Wpk      = (uint4*)ws;                     // 4 MB bf16-packed weights
  uint4* stk4     = (uint4*)(ws + 4194304);         // 128 MiB fp16 shat [t>>2][f][t&3][d]
  float* pooled   = (float*)(ws + 138412032);       // 512 KB
  float* hw_pre   = (float*)(ws + 138936320);       // 16 KB
  float* sk_pre   = (float*)(ws + 138952704);       // 2 KB
  float* wsel     = (float*)(ws + 138954752);       // 2 KB

  k_prep<<<dim3(32,8), 256, 0, stream>>>(w2, wgm, Wpk, pooled, hw_pre, sk_pre);
  k_pass1<<<dim3(64,32), 512, 0, stream>>>(x, w1, b1, b2, bg, wsk, bsk, lng, lnb,
                                           Wpk, pooled, stk4);
  k_pass2a<<<dim3(128), 256, 0, stream>>>(pooled, W1, Wsm, hw_pre, sk_pre);
  k_pass2b<<<16, 64, 0, stream>>>(hw_pre, sk_pre, B1, W2, B2, Wg, Bg, Bs, LNg, LNb, out, wsel);
  k_comb<<<2048, 256, 0, stream>>>(stk4, wsel, out);
}